// Round 6
// baseline (409.455 us; speedup 1.0000x reference)
//
#include <hip/hip_runtime.h>

typedef unsigned int u32;
typedef int  v4i  __attribute__((ext_vector_type(4)));
typedef u32  u32x4 __attribute__((ext_vector_type(4)));

#define WSCALE 512.0f
#define INV16S (1.0f / 8192.0f)   // 1/(16*WSCALE)

#define X8_BYTES (16*112*112*64)  // 12845056
#define WQ_MAIN  36864
#define WQ_PAD   5120             // zero pad: prefetch overrun + OOB staging source

// ---- pre-pass 1: fp32 OIHW (64,64,3,3) -> int8 A-fragment-linear + zero pad ----
// wq[((tap*4+m)*64 + lane)*16 + u] = q512(w[o=16m+(lane&15)][c=(lane>>4)*16+u][tap])
__global__ void wprep_kernel(const float* __restrict__ w, signed char* __restrict__ wq) {
  int i = blockIdx.x * 256 + threadIdx.x;       // grid 164*256 = 41984
  if (i < WQ_MAIN) {
    int u = i & 15, lane = (i >> 4) & 63, m = (i >> 10) & 3, tap = i >> 12;
    int p = lane & 15, kg = lane >> 4;
    int o = m * 16 + p, c = kg * 16 + u;
    int r = tap / 3, s = tap - 3 * r;
    float v = w[((o * 64 + c) * 3 + r) * 3 + s];
    float q = rintf(v * WSCALE);
    q = fminf(fmaxf(q, -127.0f), 127.0f);
    wq[i] = (signed char)(int)q;
  } else if (i < WQ_MAIN + WQ_PAD) {
    wq[i] = 0;
  }
}

// ---- pre-pass 2: x NCHW f32 -> x8 NHWC int8 (clamp + trunc), LDS transpose ----
__global__ void xprep_kernel(const float* __restrict__ x, signed char* __restrict__ x8) {
  __shared__ unsigned char l8[112 * 68];        // px stride 68 B (bank spread)
  const int tid = threadIdx.x;
  const int b = blockIdx.x / 112, h = blockIdx.x - (blockIdx.x / 112) * 112;
  const float* xrow = x + (b * 64 * 112 + h) * 112;   // + c*12544 + w
  #pragma unroll
  for (int k = 0; k < 32; ++k) {
    int e = k * 256 + tid;
    int c = e >> 7, ww = e & 127;
    if (ww < 112) {
      float v = xrow[c * 12544 + ww];
      v = fminf(fmaxf(v, -128.0f), 127.0f);
      l8[ww * 68 + c] = (unsigned char)((int)v & 255);   // trunc-toward-zero, 2's compl
    }
  }
  __syncthreads();
  signed char* orow = x8 + (b * 112 + h) * 7168;
  #pragma unroll
  for (int k = 0; k < 2; ++k) {
    int e = k * 256 + tid;
    if (e < 448) {
      int px = e >> 2, cg = e & 3;
      u32x4 v;
      #pragma unroll
      for (int i2 = 0; i2 < 4; ++i2)
        v[i2] = *(const u32*)&l8[px * 68 + cg * 16 + i2 * 4];
      *(u32x4*)(orow + px * 64 + cg * 16) = v;   // coalesced NHWC store
    }
  }
}

// ---- main: 4x16 px tile, 8 waves, wave = (bit-pair bp, m-pair mp); acc=64 regs ----
__launch_bounds__(512, 4)
__global__ void conv_kernel(const signed char* __restrict__ x8,
                            const signed char* __restrict__ wq,
                            const float* __restrict__ bias,
                            float* __restrict__ out) {
  __shared__ __align__(16) unsigned char patch8[108 * 80];  // [px][64ch], stride 80
  __shared__ float red[4 * 64 * 17];                        // [row][o] stride 17 f32

  const int tid  = threadIdx.x;
  const int lane = tid & 63, wid = tid >> 6;
  const int bid  = blockIdx.x;
  const int b    = bid / 196;
  const int rem  = bid - b * 196;
  const int ht   = rem / 7, wt = rem - (rem / 7) * 7;
  const int h0 = ht * 4, w0 = wt * 16;
  const int p = lane & 15, kg = lane >> 4;
  const int bp = wid >> 1, mp = wid & 1;

  // zero reduction buffer
  #pragma unroll
  for (int k = 0; k < 9; ++k) { int e = tid + k * 512; if (e < 4352) red[e] = 0.0f; }

  // stage int8 patch: 108 px x 64 ch = 432 x 16B chunks, 1 ld + 1 ds_write per thread
  if (tid < 432) {
    int px = tid >> 2, cg = tid & 3;
    int ph = px / 18, pw = px - ph * 18;
    int gh = h0 + ph, gw = w0 + pw;
    const signed char* src = (gh < 112 && gw < 112)
        ? x8 + ((b * 112 + gh) * 112 + gw) * 64 + cg * 16
        : wq + WQ_MAIN;                         // 16B of zeros
    *(u32x4*)&patch8[px * 80 + cg * 16] = *(const u32x4*)src;
  }
  __syncthreads();

  v4i acc[4][2][2];                             // [row][bit-in-pair][ml]
  #pragma unroll
  for (int r2 = 0; r2 < 4; ++r2)
    #pragma unroll
    for (int i2 = 0; i2 < 2; ++i2)
      #pragma unroll
      for (int j2 = 0; j2 < 2; ++j2)
        acc[r2][i2][j2] = (v4i){0, 0, 0, 0};

  const signed char* ap = wq + (mp * 2) * 1024 + lane * 16;   // global, L2-resident
  const unsigned char* pt = patch8 + p * 80 + kg * 16;
  v4i a0 = *(const v4i*)ap;
  v4i a1 = *(const v4i*)(ap + 1024);

  #pragma unroll 1
  for (int tap = 0; tap < 9; ++tap) {
    v4i n0 = *(const v4i*)(ap + (tap + 1) * 4096);          // prefetch next tap
    v4i n1 = *(const v4i*)(ap + (tap + 1) * 4096 + 1024);   // (overruns into zero pad)
    int r = (0x2A540u >> (tap * 2)) & 3;                    // tap -> kernel row
    const unsigned char* ptt = pt + tap * 80 + r * 1200;    // = (r*18+cs)*80
    #pragma unroll
    for (int row = 0; row < 4; ++row) {
      u32x4 wb = *(const u32x4*)(ptt + row * 1440);
      v4i b0, b1;
      #pragma unroll
      for (int i2 = 0; i2 < 4; ++i2) {
        b0[i2] = (int)((wb[i2] >> bp) & 0x01010101u);
        b1[i2] = (int)((wb[i2] >> (bp + 4)) & 0x01010101u);
      }
      acc[row][0][0] = __builtin_amdgcn_mfma_i32_16x16x64_i8(a0, b0, acc[row][0][0], 0, 0, 0);
      acc[row][0][1] = __builtin_amdgcn_mfma_i32_16x16x64_i8(a1, b0, acc[row][0][1], 0, 0, 0);
      acc[row][1][0] = __builtin_amdgcn_mfma_i32_16x16x64_i8(a0, b1, acc[row][1][0], 0, 0, 0);
      acc[row][1][1] = __builtin_amdgcn_mfma_i32_16x16x64_i8(a1, b1, acc[row][1][1], 0, 0, 0);
    }
    a0 = n0; a1 = n1;
  }

  // fold bit-pair: per-bit quantize, weight, pairwise sum (exact ints) -> LDS atomic add
  const float pw0 = (float)(16 << bp);
  const float pw1 = (bp == 3) ? -2048.0f : (float)(16 << (bp + 4));
  #pragma unroll
  for (int row = 0; row < 4; ++row)
    #pragma unroll
    for (int ml = 0; ml < 2; ++ml) {
      const int obase = (mp * 2 + ml) * 16 + kg * 4;
      #pragma unroll
      for (int j = 0; j < 4; ++j) {
        float q0 = fminf(fmaxf(rintf((float)acc[row][0][ml][j] * INV16S), -128.0f), 127.0f);
        float q1 = fminf(fmaxf(rintf((float)acc[row][1][ml][j] * INV16S), -128.0f), 127.0f);
        atomicAdd(&red[(row * 64 + obase + j) * 17 + p], fmaf(pw0, q0, pw1 * q1));
      }
    }
  __syncthreads();

  // read back, add bias, coalesced store
  #pragma unroll
  for (int k = 0; k < 8; ++k) {
    int e = tid + k * 512;
    int row = e >> 10, idx = e & 1023, o = idx >> 4, col = idx & 15;
    int orow = h0 + row, ocol = w0 + col;
    if (orow < 110 && ocol < 110)
      out[((b * 64 + o) * 110 + orow) * 110 + ocol] = red[(row * 64 + o) * 17 + col] + bias[o];
  }
}

extern "C" void kernel_launch(void* const* d_in, const int* in_sizes, int n_in,
                              void* d_out, int out_size, void* d_ws, size_t ws_size,
                              hipStream_t stream) {
  const float* x    = (const float*)d_in[0];
  const float* w    = (const float*)d_in[1];
  const float* bias = (const float*)d_in[2];
  float* out = (float*)d_out;
  signed char* x8 = (signed char*)d_ws;
  signed char* wq = x8 + X8_BYTES;

  hipLaunchKernelGGL(wprep_kernel, dim3(164), dim3(256), 0, stream, w, wq);
  hipLaunchKernelGGL(xprep_kernel, dim3(16 * 112), dim3(256), 0, stream, x, x8);
  // grid: 16 batches x 28 h-tiles(4 rows) x 7 w-tiles(16 cols)
  hipLaunchKernelGGL(conv_kernel, dim3(16 * 28 * 7), dim3(512), 0, stream, x8, wq, bias, out);
}

// Round 9
// 402.420 us; speedup vs baseline: 1.0175x; 1.0175x over previous
//
#include <hip/hip_runtime.h>

typedef unsigned int u32;
typedef int  v4i  __attribute__((ext_vector_type(4)));
typedef u32  u32x4 __attribute__((ext_vector_type(4)));

#define WSCALE 512.0f
#define INV16S (1.0f / 8192.0f)   // 1/(16*WSCALE)

#define X8_BYTES (16*112*112*64)  // 12845056
#define WQ_MAIN  36864
#define WQ_PAD   1024             // zero source for OOB staging

// ---- pre-pass 1: fp32 OIHW (64,64,3,3) -> int8 A-fragment-linear + zero pad ----
// wq[((tap*4+m)*64 + lane)*16 + u] = q512(w[o=16m+(lane&15)][c=(lane>>4)*16+u][tap])
__global__ void wprep_kernel(const float* __restrict__ w, signed char* __restrict__ wq) {
  int i = blockIdx.x * 256 + threadIdx.x;       // grid 149*256 = 38144
  if (i < WQ_MAIN) {
    int u = i & 15, lane = (i >> 4) & 63, m = (i >> 10) & 3, tap = i >> 12;
    int p = lane & 15, kg = lane >> 4;
    int o = m * 16 + p, c = kg * 16 + u;
    int r = tap / 3, s = tap - 3 * r;
    float v = w[((o * 64 + c) * 3 + r) * 3 + s];
    float q = rintf(v * WSCALE);
    q = fminf(fmaxf(q, -127.0f), 127.0f);
    wq[i] = (signed char)(int)q;
  } else if (i < WQ_MAIN + WQ_PAD) {
    wq[i] = 0;
  }
}

// ---- pre-pass 2: x NCHW f32 -> x8 NHWC int8 (clamp + trunc), LDS transpose ----
__global__ void xprep_kernel(const float* __restrict__ x, signed char* __restrict__ x8) {
  __shared__ unsigned char l8[112 * 68];        // px stride 68 B (bank spread)
  const int tid = threadIdx.x;
  const int b = blockIdx.x / 112, h = blockIdx.x - (blockIdx.x / 112) * 112;
  const float* xrow = x + (b * 64 * 112 + h) * 112;   // + c*12544 + w
  #pragma unroll
  for (int k = 0; k < 32; ++k) {
    int e = k * 256 + tid;
    int c = e >> 7, ww = e & 127;
    if (ww < 112) {
      float v = xrow[c * 12544 + ww];
      v = fminf(fmaxf(v, -128.0f), 127.0f);
      l8[ww * 68 + c] = (unsigned char)((int)v & 255);   // trunc-toward-zero, 2's compl
    }
  }
  __syncthreads();
  signed char* orow = x8 + (b * 112 + h) * 7168;
  #pragma unroll
  for (int k = 0; k < 2; ++k) {
    int e = k * 256 + tid;
    if (e < 448) {
      int px = e >> 2, cg = e & 3;
      u32x4 v;
      #pragma unroll
      for (int i2 = 0; i2 < 4; ++i2)
        v[i2] = *(const u32*)&l8[px * 68 + cg * 16 + i2 * 4];
      *(u32x4*)(orow + px * 64 + cg * 16) = v;   // coalesced NHWC store
    }
  }
}

// ---- main: 4x16 px tile x 32 oc per block; 8 waves = (bp 0..3, ml 0..1) ----
// wave: bits {bp, bp+4}, out-channels m=2*mp+ml (16 o). A in registers, LDS-only inner loop.
__launch_bounds__(512, 4)
__global__ void conv_kernel(const signed char* __restrict__ x8,
                            const signed char* __restrict__ wq,
                            const float* __restrict__ bias,
                            float* __restrict__ out) {
  __shared__ __align__(16) unsigned char patch8[108 * 80];  // [px][64ch], stride 80
  __shared__ float red[4 * 32 * 18];                        // [row][o_local] stride 18 f32

  const int tid  = threadIdx.x;
  const int lane = tid & 63, wid = tid >> 6;
  const int bid  = blockIdx.x;
  const int mp   = bid & 1;
  const int tb   = bid >> 1;
  const int b    = tb / 196;
  const int rem  = tb - b * 196;
  const int ht   = rem / 7, wt = rem - (rem / 7) * 7;
  const int h0 = ht * 4, w0 = wt * 16;
  const int p = lane & 15, kg = lane >> 4;
  const int bp = wid >> 1, ml = wid & 1;
  const int m = mp * 2 + ml;

  // zero reduction buffer (2304 f32)
  #pragma unroll
  for (int k = 0; k < 5; ++k) { int e = tid + k * 512; if (e < 2304) red[e] = 0.0f; }

  // stage int8 patch: 108 px x 64 ch = 432 x 16B chunks
  if (tid < 432) {
    int px = tid >> 2, cg = tid & 3;
    int ph = px / 18, pw = px - ph * 18;
    int gh = h0 + ph, gw = w0 + pw;
    const signed char* src = (gh < 112 && gw < 112)
        ? x8 + ((b * 112 + gh) * 112 + gw) * 64 + cg * 16
        : wq + WQ_MAIN;                         // 16B of zeros
    *(u32x4*)&patch8[px * 80 + cg * 16] = *(const u32x4*)src;
  }
  __syncthreads();

  v4i acc[4][2];                                // [row][bit-in-pair]
  #pragma unroll
  for (int r2 = 0; r2 < 4; ++r2)
    #pragma unroll
    for (int i2 = 0; i2 < 2; ++i2)
      acc[r2][i2] = (v4i){0, 0, 0, 0};

  const signed char* abase = wq + m * 1024 + lane * 16;     // + tap*4096
  const unsigned char* pt  = patch8 + p * 80 + kg * 16;

  // A for kernel-row 0 (taps 0..2): 3 x v4i in registers
  v4i aC0 = *(const v4i*)(abase);
  v4i aC1 = *(const v4i*)(abase + 4096);
  v4i aC2 = *(const v4i*)(abase + 8192);

  #pragma unroll
  for (int kr = 0; kr < 3; ++kr) {
    v4i aN0, aN1, aN2;
    if (kr < 2) {                               // prefetch next kernel-row's A
      const signed char* nb = abase + (kr + 1) * 12288;
      aN0 = *(const v4i*)(nb);
      aN1 = *(const v4i*)(nb + 4096);
      aN2 = *(const v4i*)(nb + 8192);
    }
    #pragma unroll
    for (int row = 0; row < 4; ++row) {
      const unsigned char* pr = pt + (row + kr) * 1440;   // pixel row (row+kr)
      #pragma unroll
      for (int ts = 0; ts < 3; ++ts) {
        u32x4 wb = *(const u32x4*)(pr + ts * 80);
        v4i b0, b1;
        #pragma unroll
        for (int i2 = 0; i2 < 4; ++i2) {
          b0[i2] = (int)((wb[i2] >> bp) & 0x01010101u);
          b1[i2] = (int)((wb[i2] >> (bp + 4)) & 0x01010101u);
        }
        v4i a = (ts == 0) ? aC0 : (ts == 1) ? aC1 : aC2;
        acc[row][0] = __builtin_amdgcn_mfma_i32_16x16x64_i8(a, b0, acc[row][0], 0, 0, 0);
        acc[row][1] = __builtin_amdgcn_mfma_i32_16x16x64_i8(a, b1, acc[row][1], 0, 0, 0);
      }
    }
    aC0 = aN0; aC1 = aN1; aC2 = aN2;
  }

  // fold bit-pair: per-bit quantize, weight, pairwise sum (exact ints) -> LDS atomic add
  const float pw0 = (float)(16 << bp);
  const float pw1 = (bp == 3) ? -2048.0f : (float)(16 << (bp + 4));
  #pragma unroll
  for (int row = 0; row < 4; ++row) {
    const int obase = ml * 16 + kg * 4;
    #pragma unroll
    for (int j = 0; j < 4; ++j) {
      float q0 = fminf(fmaxf(rintf((float)acc[row][0][j] * INV16S), -128.0f), 127.0f);
      float q1 = fminf(fmaxf(rintf((float)acc[row][1][j] * INV16S), -128.0f), 127.0f);
      atomicAdd(&red[(row * 32 + obase + j) * 18 + p], fmaf(pw0, q0, pw1 * q1));
    }
  }
  __syncthreads();

  // read back, add bias, coalesced store (2048 vals / 512 thr = 4 each)
  #pragma unroll
  for (int k = 0; k < 4; ++k) {
    int e = tid + k * 512;
    int row = e >> 9, idx = e & 511, o = idx >> 4, col = idx & 15;
    int og   = mp * 32 + o;
    int orow = h0 + row, ocol = w0 + col;
    if (orow < 110 && ocol < 110)
      out[((b * 64 + og) * 110 + orow) * 110 + ocol] = red[(row * 32 + o) * 18 + col] + bias[og];
  }
}

extern "C" void kernel_launch(void* const* d_in, const int* in_sizes, int n_in,
                              void* d_out, int out_size, void* d_ws, size_t ws_size,
                              hipStream_t stream) {
  const float* x    = (const float*)d_in[0];
  const float* w    = (const float*)d_in[1];
  const float* bias = (const float*)d_in[2];
  float* out = (float*)d_out;
  signed char* x8 = (signed char*)d_ws;
  signed char* wq = x8 + X8_BYTES;

  hipLaunchKernelGGL(wprep_kernel, dim3(149), dim3(256), 0, stream, w, wq);
  hipLaunchKernelGGL(xprep_kernel, dim3(16 * 112), dim3(256), 0, stream, x, x8);
  // grid: 16 batches x 28 ht x 7 wt x 2 mp
  hipLaunchKernelGGL(conv_kernel, dim3(16 * 28 * 7 * 2), dim3(512), 0, stream, x8, wq, bias, out);
}